// Round 11
// baseline (118.005 us; speedup 1.0000x reference)
//
#include <hip/hip_runtime.h>

typedef float f32x4 __attribute__((ext_vector_type(4)));
typedef float f32x16 __attribute__((ext_vector_type(16)));
typedef short s16x8 __attribute__((ext_vector_type(8)));
typedef short s16x4 __attribute__((ext_vector_type(4)));
typedef unsigned short u16;

#define NB 8
#define NC 64
#define NN 4096

// float -> bf16 bits, round-to-nearest-even
__device__ __forceinline__ u16 f2bf_rne(float f) {
    unsigned u = __float_as_uint(f);
    u += 0x7FFFu + ((u >> 16) & 1u);
    return (u16)(u >> 16);
}
__device__ __forceinline__ float bf2f(u16 v) {
    return __uint_as_float(((unsigned)v) << 16);
}
// pack two f32 -> one u32 of 2 bf16 (RNE), lo = first arg
__device__ __forceinline__ unsigned cvt_pk_bf16(float lo, float hi) {
    unsigned r;
    asm("v_cvt_pk_bf16_f32 %0, %1, %2" : "=v"(r) : "v"(lo), "v"(hi));
    return r;
}
// swap: a' = {a.lanes0-31, b.lanes0-31}, b' = {a.lanes32-63, b.lanes32-63}
__device__ __forceinline__ void pl32_swap(unsigned &a, unsigned &b) {
    asm("v_permlane32_swap_b32 %0, %1" : "+v"(a), "+v"(b));
}
// 2^x on the FULL-RATE VALU pipe (no v_exp_f32): range-reduce + cubic.
// rel err <= 6e-4 (bf16 P quantization is 4e-3; errors partly cancel in P/l).
// 7 ops ~14 cyc vs trans-pipe exp (8-32 cyc, shared-issue) — A/B vs R8 tests
// whether the transcendental pipe is attention's ~30us wall.
__device__ __forceinline__ float exp2_poly(float x) {
    float n = __builtin_rintf(x);
    float f = x - n;
    float p = __builtin_fmaf(f, __builtin_fmaf(f, __builtin_fmaf(f,
                  0.0555041086f, 0.2402265069f), 0.6931471806f), 1.0f);
    return __builtin_amdgcn_ldexpf(p, (int)n);   // v_ldexp_f32: exact 2^n scale
}

#define Z16 ((f32x16){0.f,0.f,0.f,0.f,0.f,0.f,0.f,0.f,0.f,0.f,0.f,0.f,0.f,0.f,0.f,0.f})

// ---------------------------------------------------------------------------
// Kernel 1 (unchanged): W' = [Wh(64); Wf(8); Wg(8)] @ x[b] via MFMA.
// Wf pre-scaled by log2(e). Qw/Gw: [B][N][16] bf16, top 8 zeroed. H written
// in PV-B-fragment order (Hf). Grid (b, n-tile) -> batch b pinned to XCD b.
// ---------------------------------------------------------------------------
__global__ __launch_bounds__(256, 4)
void precompute_qgh(const float* __restrict__ x,
                    const float* __restrict__ Wf,
                    const float* __restrict__ Wg,
                    const float* __restrict__ Wh,
                    u16* __restrict__ Qw, u16* __restrict__ Gw,
                    u16* __restrict__ Hf)
{
    const int b  = blockIdx.x;           // b fastest -> XCD = b
    const int n0 = blockIdx.y * 64;
    const int t  = threadIdx.x;
    const int wave = t >> 6, lane = t & 63, col = lane & 15, quad = lane >> 4;
    const float* xb = x + (size_t)b * NC * NN;

    __shared__ __align__(16) u16 WL[80][72];
    __shared__ __align__(16) u16 XT[64][72];

    #pragma unroll
    for (int r5 = 0; r5 < 5; r5++) {
        int v = r5 * 256 + t;
        int m = v >> 4, ks = (v & 15) << 2;
        const float* src = (m < 64) ? (Wh + m * 64 + ks)
                         : (m < 72) ? (Wf + (m - 64) * 64 + ks)
                                    : (Wg + (m - 72) * 64 + ks);
        const float scl = (m >= 64 && m < 72) ? 1.44269504088896f : 1.0f;
        f32x4 wv = *(const f32x4*)src;
        *(unsigned*)&WL[m][ks]     = (unsigned)f2bf_rne(wv[0] * scl) | ((unsigned)f2bf_rne(wv[1] * scl) << 16);
        *(unsigned*)&WL[m][ks + 2] = (unsigned)f2bf_rne(wv[2] * scl) | ((unsigned)f2bf_rne(wv[3] * scl) << 16);
    }
    #pragma unroll
    for (int r4 = 0; r4 < 4; r4++) {
        int v = r4 * 256 + t;
        int c = v >> 4, ns = (v & 15) << 2;
        f32x4 xv = *(const f32x4*)(xb + (size_t)c * NN + n0 + ns);
        #pragma unroll
        for (int e = 0; e < 4; e++) XT[ns + e][c] = f2bf_rne(xv[e]);
    }
    __syncthreads();

    const int n = n0 + wave * 16 + col;
    s16x8 bfrag[2], afrag[5][2];
    #pragma unroll
    for (int s = 0; s < 2; s++)
        bfrag[s] = *(const s16x8*)&XT[wave * 16 + col][s * 32 + quad * 8];
    #pragma unroll
    for (int mt = 0; mt < 5; mt++)
        #pragma unroll
        for (int s = 0; s < 2; s++)
            afrag[mt][s] = *(const s16x8*)&WL[mt * 16 + col][s * 32 + quad * 8];

    f32x4 d[5];
    #pragma unroll
    for (int mt = 0; mt < 5; mt++) d[mt] = (f32x4){0.f, 0.f, 0.f, 0.f};
    #pragma unroll
    for (int s = 0; s < 2; s++)
        #pragma unroll
        for (int mt = 0; mt < 5; mt++)
            d[mt] = __builtin_amdgcn_mfma_f32_16x16x32_bf16(afrag[mt][s], bfrag[s], d[mt], 0, 0, 0);

    union { s16x4 v; u16 e[4]; } pk4;
    #pragma unroll
    for (int r = 0; r < 4; r++) pk4.e[r] = f2bf_rne(d[4][r]);
    u16* qgbase = (quad < 2 ? Qw : Gw) + ((size_t)b * NN + n) * 16;
    *(s16x4*)(qgbase + (quad & 1) * 4) = pk4.v;
    if ((quad & 1) == 0) {
        s16x8 z;
        #pragma unroll
        for (int qz = 0; qz < 8; qz++) ((u16*)&z)[qz] = 0;
        *(s16x8*)(qgbase + 8) = z;
    }

    __syncthreads();
    u16 (*Hl)[72] = WL;                    // reuse WL space
    #pragma unroll
    for (int mt = 0; mt < 4; mt++)
        #pragma unroll
        for (int r = 0; r < 4; r++)
            Hl[mt * 16 + quad * 4 + r][wave * 16 + col] = f2bf_rne(d[mt][r]);
    __syncthreads();

    u16* HfB = Hf + (size_t)b * NC * NN + (size_t)blockIdx.y * 4096;
    #pragma unroll
    for (int it = 0; it < 2; it++) {
        int u = it * 256 + t;
        int s_local = u >> 7, chalf = (u >> 6) & 1, l = u & 63;
        s16x8 vv = *(const s16x8*)&Hl[chalf * 32 + (l & 31)][s_local * 16 + (l >> 5) * 8];
        *(s16x8*)(HfB + (size_t)((s_local * 2 + chalf) * 512 + l * 8)) = vv;
    }
}

// ---------------------------------------------------------------------------
// Kernel 2 v11: EXACTLY the R8 structure (best total: 99.4us) with ONE
// change: exp2 moved off the transcendental pipe onto the full-rate VALU
// (exp2_poly). Clean A/B: if the trans pipe (v_exp_f32 at low rate, shared
// VALU issue port) was the ~30us wall that made R7-R10's traffic/occupancy
// changes all neutral, this drops attention ~2x. If neutral/worse, the
// per-tile issue recipe is at its floor and we're at the ceiling.
// Grid (8, 64), 256-thr blocks, batch->XCD pinned; wave = j-quarter,
// 2 Q-tiles/wave; coalesced fragment-ordered Hf loads; depth-1 reg prefetch.
// ---------------------------------------------------------------------------
__global__ __launch_bounds__(256, 2)
void attention_fused(const u16* __restrict__ Qw, const u16* __restrict__ Gw,
                     const u16* __restrict__ Hf,
                     const float* __restrict__ x, const float* __restrict__ gamma,
                     float* __restrict__ out)
{
    const int b  = blockIdx.x;           // b fastest -> XCD = b
    const int i0 = blockIdx.y * 64;
    const int t  = threadIdx.x;
    const int wave = t >> 6, lane = t & 63, col = lane & 31, hi = lane >> 5;

    __shared__ __align__(16) float R0a[64][36];   // tile0 slabs
    __shared__ __align__(16) float R1a[64][36];
    __shared__ __align__(16) float R0b[64][36];   // tile1 slabs
    __shared__ __align__(16) float R1b[64][36];
    __shared__ float Ls[2][4][32];
    __shared__ float Sc[2][32];

    const u16* Qb  = Qw + (size_t)b * NN * 16;
    const u16* Gb  = Gw + (size_t)b * NN * 16;
    const u16* Hfb = Hf + (size_t)b * NC * NN;

    const float g = gamma[0];

    // Two Q fragments: B[k=hi*8+kk][n=i]; k>=8 zeros from layout
    s16x8 qf0 = *(const s16x8*)(Qb + (size_t)(i0 + col) * 16 + hi * 8);
    s16x8 qf1 = *(const s16x8*)(Qb + (size_t)(i0 + 32 + col) * 16 + hi * 8);

    f32x16 oacc[2][2];   // [tile][chalf]; all indexing statically unrolled
    oacc[0][0] = Z16; oacc[0][1] = Z16; oacc[1][0] = Z16; oacc[1][1] = Z16;
    float ls0a = 0.f, ls0b = 0.f, ls1a = 0.f, ls1b = 0.f;

    const int jbase = wave * 1024;
    const u16* pv = Hfb + (size_t)(jbase >> 4) * 1024 + (size_t)lane * 8;

    // prefetch chunk 0: G A-frag + 4 V B-frags ([slice s2][chalf])
    s16x8 ga  = *(const s16x8*)(Gb + (size_t)(jbase + col) * 16 + hi * 8);
    s16x8 va0 = *(const s16x8*)(pv);
    s16x8 va1 = *(const s16x8*)(pv + 512);
    s16x8 va2 = *(const s16x8*)(pv + 1024);
    s16x8 va3 = *(const s16x8*)(pv + 1536);
    pv += 2048;

    for (int cc = 0; cc < 32; cc++) {
        // prefetch chunk cc+1 (last-iter overread -> adjacent ws region, benign)
        s16x8 gan = *(const s16x8*)(Gb + (size_t)(jbase + cc * 32 + 32 + col) * 16 + hi * 8);
        s16x8 vn0 = *(const s16x8*)(pv);
        s16x8 vn1 = *(const s16x8*)(pv + 512);
        s16x8 vn2 = *(const s16x8*)(pv + 1024);
        s16x8 vn3 = *(const s16x8*)(pv + 1536);
        pv += 2048;

        f32x16 S0 = __builtin_amdgcn_mfma_f32_32x32x16_bf16(ga, qf0, Z16, 0, 0, 0);
        f32x16 S1 = __builtin_amdgcn_mfma_f32_32x32x16_bf16(ga, qf1, Z16, 0, 0, 0);
        #pragma unroll
        for (int r = 0; r < 16; r++) S0[r] = exp2_poly(S0[r]);
        #pragma unroll
        for (int r = 0; r < 16; r++) S1[r] = exp2_poly(S1[r]);
        #pragma unroll
        for (int r = 0; r < 16; r += 2) {
            ls0a += S0[r]; ls0b += S0[r + 1];
            ls1a += S1[r]; ls1b += S1[r + 1];
        }

        #pragma unroll
        for (int s2 = 0; s2 < 2; s2++) {
            // tile 0 P fragment
            unsigned a0 = cvt_pk_bf16(S0[8*s2+0], S0[8*s2+1]);
            unsigned a2 = cvt_pk_bf16(S0[8*s2+4], S0[8*s2+5]);
            unsigned a1 = cvt_pk_bf16(S0[8*s2+2], S0[8*s2+3]);
            unsigned a3 = cvt_pk_bf16(S0[8*s2+6], S0[8*s2+7]);
            pl32_swap(a0, a2);
            pl32_swap(a1, a3);
            union { s16x8 v; unsigned u[4]; } p0;
            p0.u[0] = a0; p0.u[1] = a1; p0.u[2] = a2; p0.u[3] = a3;
            // tile 1 P fragment
            unsigned b0 = cvt_pk_bf16(S1[8*s2+0], S1[8*s2+1]);
            unsigned b2 = cvt_pk_bf16(S1[8*s2+4], S1[8*s2+5]);
            unsigned b1 = cvt_pk_bf16(S1[8*s2+2], S1[8*s2+3]);
            unsigned b3 = cvt_pk_bf16(S1[8*s2+6], S1[8*s2+7]);
            pl32_swap(b0, b2);
            pl32_swap(b1, b3);
            union { s16x8 v; unsigned u[4]; } p1;
            p1.u[0] = b0; p1.u[1] = b1; p1.u[2] = b2; p1.u[3] = b3;
            // V fragments shared by both tiles
            oacc[0][0] = __builtin_amdgcn_mfma_f32_32x32x16_bf16(p0.v, s2 ? va2 : va0, oacc[0][0], 0, 0, 0);
            oacc[0][1] = __builtin_amdgcn_mfma_f32_32x32x16_bf16(p0.v, s2 ? va3 : va1, oacc[0][1], 0, 0, 0);
            oacc[1][0] = __builtin_amdgcn_mfma_f32_32x32x16_bf16(p1.v, s2 ? va2 : va0, oacc[1][0], 0, 0, 0);
            oacc[1][1] = __builtin_amdgcn_mfma_f32_32x32x16_bf16(p1.v, s2 ? va3 : va1, oacc[1][1], 0, 0, 0);
        }
        ga = gan; va0 = vn0; va1 = vn1; va2 = vn2; va3 = vn3;
    }

    float lsum0 = ls0a + ls0b;
    float lsum1 = ls1a + ls1b;
    // combine hi-halves (lane i and i+32 hold disjoint j'-sets)
    {
        unsigned a = __float_as_uint(lsum0), c2 = a;
        pl32_swap(a, c2);
        lsum0 = __uint_as_float(a) + __uint_as_float(c2);
        unsigned d = __float_as_uint(lsum1), e2 = d;
        pl32_swap(d, e2);
        lsum1 = __uint_as_float(d) + __uint_as_float(e2);
    }

    // ---- epilogue: per-tile tree-combine of 4 wave partials (O^T layout) ----
    if (hi == 0) { Ls[0][wave][col] = lsum0; Ls[1][wave][col] = lsum1; }
    if (wave & 1) {
        float (*Ra)[36] = (wave == 1) ? R0a : R1a;
        float (*Rb)[36] = (wave == 1) ? R0b : R1b;
        #pragma unroll
        for (int ch = 0; ch < 2; ch++)
            #pragma unroll
            for (int r = 0; r < 16; r++) {
                int ii = (r & 3) + 8 * (r >> 2) + 4 * hi;
                Ra[ch * 32 + col][ii] = oacc[0][ch][r];
                Rb[ch * 32 + col][ii] = oacc[1][ch][r];
            }
    }
    __syncthreads();
    if (!(wave & 1)) {
        float (*Ra)[36] = (wave == 0) ? R0a : R1a;
        float (*Rb)[36] = (wave == 0) ? R0b : R1b;
        #pragma unroll
        for (int ch = 0; ch < 2; ch++)
            #pragma unroll
            for (int r = 0; r < 16; r++) {
                int ii = (r & 3) + 8 * (r >> 2) + 4 * hi;
                oacc[0][ch][r] += Ra[ch * 32 + col][ii];
                oacc[1][ch][r] += Rb[ch * 32 + col][ii];
            }
    }
    if (wave == 1 && hi == 0)
        Sc[0][col] = g / (Ls[0][0][col] + Ls[0][1][col] + Ls[0][2][col] + Ls[0][3][col]);
    if (wave == 3 && hi == 0)
        Sc[1][col] = g / (Ls[1][0][col] + Ls[1][1][col] + Ls[1][2][col] + Ls[1][3][col]);
    if (wave == 2) {
        #pragma unroll
        for (int ch = 0; ch < 2; ch++)
            #pragma unroll
            for (int r = 0; r < 16; r++) {
                int ii = (r & 3) + 8 * (r >> 2) + 4 * hi;
                R1a[ch * 32 + col][ii] = oacc[0][ch][r];
                R1b[ch * 32 + col][ii] = oacc[1][ch][r];
            }
    }
    __syncthreads();
    if (wave == 0) {
        #pragma unroll
        for (int ch = 0; ch < 2; ch++)
            #pragma unroll
            for (int r = 0; r < 16; r++) {
                int ii = (r & 3) + 8 * (r >> 2) + 4 * hi;
                R0a[ch * 32 + col][ii] = oacc[0][ch][r] + R1a[ch * 32 + col][ii];
                R0b[ch * 32 + col][ii] = oacc[1][ch][r] + R1b[ch * 32 + col][ii];
            }
    }
    __syncthreads();

    // store: 64 c x 64 i; tile uniform per thread (q<2 -> tile0)
    const int oc = t >> 2, q = t & 3;
    float (*slab)[36] = (q < 2) ? R0a : R0b;
    const float* sc = Sc[q >> 1];
    const float* xr = x   + ((size_t)b * NC + oc) * NN + i0;
    float*    orow  = out + ((size_t)b * NC + oc) * NN + i0;
    #pragma unroll
    for (int e = 0; e < 4; e++) {
        const int il = q * 16 + e * 4;        // 0..63 within block's i-range
        const int ii = (q & 1) * 16 + e * 4;  // 0..31 within tile
        f32x4 o = *(const f32x4*)&slab[oc][ii];
        f32x4 xv = *(const f32x4*)(xr + il);
        f32x4 rv;
        #pragma unroll
        for (int k = 0; k < 4; k++) rv[k] = o[k] * sc[ii + k] + xv[k];
        *(f32x4*)(orow + il) = rv;
    }
}

extern "C" void kernel_launch(void* const* d_in, const int* in_sizes, int n_in,
                              void* d_out, int out_size, void* d_ws, size_t ws_size,
                              hipStream_t stream) {
    const float* x     = (const float*)d_in[0];
    const float* Wf    = (const float*)d_in[1];
    const float* Wg    = (const float*)d_in[2];
    const float* Wh    = (const float*)d_in[3];
    const float* gamma = (const float*)d_in[4];
    float* out = (float*)d_out;

    // layout: Hf first, then Gw, then Qw — so last-iteration prefetch
    // overreads (Hf -> Gw, Gw -> Qw) stay inside the workspace.
    u16* Hf = (u16*)d_ws;                       // [B][256 slices][2][512] frag-order
    u16* Gw = Hf + (size_t)NB * NC * NN;        // [B][N][16] (top 8 zeroed)
    u16* Qw = Gw + (size_t)NB * NN * 16;        // [B][N][16] (top 8 zeroed)

    precompute_qgh<<<dim3(NB, 64), 256, 0, stream>>>(x, Wf, Wg, Wh, Qw, Gw, Hf);
    attention_fused<<<dim3(NB, 64), 256, 0, stream>>>(Qw, Gw, Hf, x, gamma, out);
}

// Round 12
// 106.215 us; speedup vs baseline: 1.1110x; 1.1110x over previous
//
#include <hip/hip_runtime.h>

typedef float f32x4 __attribute__((ext_vector_type(4)));
typedef float f32x16 __attribute__((ext_vector_type(16)));
typedef short s16x8 __attribute__((ext_vector_type(8)));
typedef short s16x4 __attribute__((ext_vector_type(4)));
typedef unsigned short u16;

#define NB 8
#define NC 64
#define NN 4096

// float -> bf16 bits, round-to-nearest-even
__device__ __forceinline__ u16 f2bf_rne(float f) {
    unsigned u = __float_as_uint(f);
    u += 0x7FFFu + ((u >> 16) & 1u);
    return (u16)(u >> 16);
}
__device__ __forceinline__ float bf2f(u16 v) {
    return __uint_as_float(((unsigned)v) << 16);
}
// pack two f32 -> one u32 of 2 bf16 (RNE), lo = first arg
__device__ __forceinline__ unsigned cvt_pk_bf16(float lo, float hi) {
    unsigned r;
    asm("v_cvt_pk_bf16_f32 %0, %1, %2" : "=v"(r) : "v"(lo), "v"(hi));
    return r;
}
// swap: a' = {a.lanes0-31, b.lanes0-31}, b' = {a.lanes32-63, b.lanes32-63}
__device__ __forceinline__ void pl32_swap(unsigned &a, unsigned &b) {
    asm("v_permlane32_swap_b32 %0, %1" : "+v"(a), "+v"(b));
}
// 2^x via the hardware transcendental unit (v_exp_f32).
// (R11 A/B: VALU polynomial exp was 17us SLOWER — trans pipe is not the wall.)
__device__ __forceinline__ float exp2_hw(float x) {
    return __builtin_amdgcn_exp2f(x);
}

#define Z16 ((f32x16){0.f,0.f,0.f,0.f,0.f,0.f,0.f,0.f,0.f,0.f,0.f,0.f,0.f,0.f,0.f,0.f})

// ---------------------------------------------------------------------------
// Kernel 1 (unchanged): W' = [Wh(64); Wf(8); Wg(8)] @ x[b] via MFMA.
// Wf pre-scaled by log2(e). Qw/Gw: [B][N][16] bf16, top 8 zeroed. H written
// in PV-B-fragment order (Hf). Grid (b, n-tile) -> batch b pinned to XCD b.
// ---------------------------------------------------------------------------
__global__ __launch_bounds__(256, 4)
void precompute_qgh(const float* __restrict__ x,
                    const float* __restrict__ Wf,
                    const float* __restrict__ Wg,
                    const float* __restrict__ Wh,
                    u16* __restrict__ Qw, u16* __restrict__ Gw,
                    u16* __restrict__ Hf)
{
    const int b  = blockIdx.x;           // b fastest -> XCD = b
    const int n0 = blockIdx.y * 64;
    const int t  = threadIdx.x;
    const int wave = t >> 6, lane = t & 63, col = lane & 15, quad = lane >> 4;
    const float* xb = x + (size_t)b * NC * NN;

    __shared__ __align__(16) u16 WL[80][72];
    __shared__ __align__(16) u16 XT[64][72];

    #pragma unroll
    for (int r5 = 0; r5 < 5; r5++) {
        int v = r5 * 256 + t;
        int m = v >> 4, ks = (v & 15) << 2;
        const float* src = (m < 64) ? (Wh + m * 64 + ks)
                         : (m < 72) ? (Wf + (m - 64) * 64 + ks)
                                    : (Wg + (m - 72) * 64 + ks);
        const float scl = (m >= 64 && m < 72) ? 1.44269504088896f : 1.0f;
        f32x4 wv = *(const f32x4*)src;
        *(unsigned*)&WL[m][ks]     = (unsigned)f2bf_rne(wv[0] * scl) | ((unsigned)f2bf_rne(wv[1] * scl) << 16);
        *(unsigned*)&WL[m][ks + 2] = (unsigned)f2bf_rne(wv[2] * scl) | ((unsigned)f2bf_rne(wv[3] * scl) << 16);
    }
    #pragma unroll
    for (int r4 = 0; r4 < 4; r4++) {
        int v = r4 * 256 + t;
        int c = v >> 4, ns = (v & 15) << 2;
        f32x4 xv = *(const f32x4*)(xb + (size_t)c * NN + n0 + ns);
        #pragma unroll
        for (int e = 0; e < 4; e++) XT[ns + e][c] = f2bf_rne(xv[e]);
    }
    __syncthreads();

    const int n = n0 + wave * 16 + col;
    s16x8 bfrag[2], afrag[5][2];
    #pragma unroll
    for (int s = 0; s < 2; s++)
        bfrag[s] = *(const s16x8*)&XT[wave * 16 + col][s * 32 + quad * 8];
    #pragma unroll
    for (int mt = 0; mt < 5; mt++)
        #pragma unroll
        for (int s = 0; s < 2; s++)
            afrag[mt][s] = *(const s16x8*)&WL[mt * 16 + col][s * 32 + quad * 8];

    f32x4 d[5];
    #pragma unroll
    for (int mt = 0; mt < 5; mt++) d[mt] = (f32x4){0.f, 0.f, 0.f, 0.f};
    #pragma unroll
    for (int s = 0; s < 2; s++)
        #pragma unroll
        for (int mt = 0; mt < 5; mt++)
            d[mt] = __builtin_amdgcn_mfma_f32_16x16x32_bf16(afrag[mt][s], bfrag[s], d[mt], 0, 0, 0);

    union { s16x4 v; u16 e[4]; } pk4;
    #pragma unroll
    for (int r = 0; r < 4; r++) pk4.e[r] = f2bf_rne(d[4][r]);
    u16* qgbase = (quad < 2 ? Qw : Gw) + ((size_t)b * NN + n) * 16;
    *(s16x4*)(qgbase + (quad & 1) * 4) = pk4.v;
    if ((quad & 1) == 0) {
        s16x8 z;
        #pragma unroll
        for (int qz = 0; qz < 8; qz++) ((u16*)&z)[qz] = 0;
        *(s16x8*)(qgbase + 8) = z;
    }

    __syncthreads();
    u16 (*Hl)[72] = WL;                    // reuse WL space
    #pragma unroll
    for (int mt = 0; mt < 4; mt++)
        #pragma unroll
        for (int r = 0; r < 4; r++)
            Hl[mt * 16 + quad * 4 + r][wave * 16 + col] = f2bf_rne(d[mt][r]);
    __syncthreads();

    u16* HfB = Hf + (size_t)b * NC * NN + (size_t)blockIdx.y * 4096;
    #pragma unroll
    for (int it = 0; it < 2; it++) {
        int u = it * 256 + t;
        int s_local = u >> 7, chalf = (u >> 6) & 1, l = u & 63;
        s16x8 vv = *(const s16x8*)&Hl[chalf * 32 + (l & 31)][s_local * 16 + (l >> 5) * 8];
        *(s16x8*)(HfB + (size_t)((s_local * 2 + chalf) * 512 + l * 8)) = vv;
    }
}

// ---------------------------------------------------------------------------
// Kernel 2 v12: R8 structure (best: 99.4us total) + ILP spend.
// R11 counters showed all pipes <56% busy, occ 17% — phase-serialized at
// 2 waves/SIMD. Occupancy is GRID-limited (512 blocks = 2 blocks/CU), so
// VGPRs are free to 256: (a) unroll-2 the chunk loop so chunk n+1's QK/exp
// overlaps chunk n's cvt/PV in-wave; (b) row-sum moved from the 55%-busy
// VALU to the 15%-busy matrix pipe via ones-A MFMA on the P fragments
// (also removes 32 adds from the exp critical path + epilogue swaps);
// (c) exp back on the trans pipe (R11 A/B: poly was slower).
// Grid (8, 64), 256-thr blocks, batch->XCD pinned; wave = j-quarter,
// 2 Q-tiles/wave; coalesced fragment-ordered Hf loads; depth-1 reg prefetch.
// ---------------------------------------------------------------------------
__global__ __launch_bounds__(256, 2)
void attention_fused(const u16* __restrict__ Qw, const u16* __restrict__ Gw,
                     const u16* __restrict__ Hf,
                     const float* __restrict__ x, const float* __restrict__ gamma,
                     float* __restrict__ out)
{
    const int b  = blockIdx.x;           // b fastest -> XCD = b
    const int i0 = blockIdx.y * 64;
    const int t  = threadIdx.x;
    const int wave = t >> 6, lane = t & 63, col = lane & 31, hi = lane >> 5;

    __shared__ __align__(16) float R0a[64][36];   // tile0 slabs
    __shared__ __align__(16) float R1a[64][36];
    __shared__ __align__(16) float R0b[64][36];   // tile1 slabs
    __shared__ __align__(16) float R1b[64][36];
    __shared__ float Ls[2][4][32];
    __shared__ float Sc[2][32];

    const u16* Qb  = Qw + (size_t)b * NN * 16;
    const u16* Gb  = Gw + (size_t)b * NN * 16;
    const u16* Hfb = Hf + (size_t)b * NC * NN;

    const float g = gamma[0];

    // Two Q fragments: B[k=hi*8+kk][n=i]; k>=8 zeros from layout
    s16x8 qf0 = *(const s16x8*)(Qb + (size_t)(i0 + col) * 16 + hi * 8);
    s16x8 qf1 = *(const s16x8*)(Qb + (size_t)(i0 + 32 + col) * 16 + hi * 8);

    s16x8 ones;
    #pragma unroll
    for (int qz = 0; qz < 8; qz++) ((u16*)&ones)[qz] = 0x3F80;   // bf16 1.0

    f32x16 oacc[2][2];   // [tile][chalf]; all indexing statically unrolled
    oacc[0][0] = Z16; oacc[0][1] = Z16; oacc[1][0] = Z16; oacc[1][1] = Z16;
    f32x16 lacc0 = Z16, lacc1 = Z16;     // row-sum accumulators (matrix pipe)

    const int jbase = wave * 1024;
    const u16* pv = Hfb + (size_t)(jbase >> 4) * 1024 + (size_t)lane * 8;

    // prefetch chunk 0: G A-frag + 4 V B-frags ([slice s2][chalf])
    s16x8 ga  = *(const s16x8*)(Gb + (size_t)(jbase + col) * 16 + hi * 8);
    s16x8 va0 = *(const s16x8*)(pv);
    s16x8 va1 = *(const s16x8*)(pv + 512);
    s16x8 va2 = *(const s16x8*)(pv + 1024);
    s16x8 va3 = *(const s16x8*)(pv + 1536);
    pv += 2048;

    #pragma unroll 2
    for (int cc = 0; cc < 32; cc++) {
        // prefetch chunk cc+1 (last-iter overread -> adjacent ws region, benign)
        s16x8 gan = *(const s16x8*)(Gb + (size_t)(jbase + cc * 32 + 32 + col) * 16 + hi * 8);
        s16x8 vn0 = *(const s16x8*)(pv);
        s16x8 vn1 = *(const s16x8*)(pv + 512);
        s16x8 vn2 = *(const s16x8*)(pv + 1024);
        s16x8 vn3 = *(const s16x8*)(pv + 1536);
        pv += 2048;

        f32x16 S0 = __builtin_amdgcn_mfma_f32_32x32x16_bf16(ga, qf0, Z16, 0, 0, 0);
        f32x16 S1 = __builtin_amdgcn_mfma_f32_32x32x16_bf16(ga, qf1, Z16, 0, 0, 0);
        #pragma unroll
        for (int r = 0; r < 16; r++) S0[r] = exp2_hw(S0[r]);
        #pragma unroll
        for (int r = 0; r < 16; r++) S1[r] = exp2_hw(S1[r]);

        #pragma unroll
        for (int s2 = 0; s2 < 2; s2++) {
            // tile 0 P fragment
            unsigned a0 = cvt_pk_bf16(S0[8*s2+0], S0[8*s2+1]);
            unsigned a2 = cvt_pk_bf16(S0[8*s2+4], S0[8*s2+5]);
            unsigned a1 = cvt_pk_bf16(S0[8*s2+2], S0[8*s2+3]);
            unsigned a3 = cvt_pk_bf16(S0[8*s2+6], S0[8*s2+7]);
            pl32_swap(a0, a2);
            pl32_swap(a1, a3);
            union { s16x8 v; unsigned u[4]; } p0;
            p0.u[0] = a0; p0.u[1] = a1; p0.u[2] = a2; p0.u[3] = a3;
            // tile 1 P fragment
            unsigned b0 = cvt_pk_bf16(S1[8*s2+0], S1[8*s2+1]);
            unsigned b2 = cvt_pk_bf16(S1[8*s2+4], S1[8*s2+5]);
            unsigned b1 = cvt_pk_bf16(S1[8*s2+2], S1[8*s2+3]);
            unsigned b3 = cvt_pk_bf16(S1[8*s2+6], S1[8*s2+7]);
            pl32_swap(b0, b2);
            pl32_swap(b1, b3);
            union { s16x8 v; unsigned u[4]; } p1;
            p1.u[0] = b0; p1.u[1] = b1; p1.u[2] = b2; p1.u[3] = b3;
            // row-sums on the matrix pipe: pb as B-operand sums over ALL
            // k=0..15 (both hi halves) -> every lacc reg = partial l[i=col]
            lacc0 = __builtin_amdgcn_mfma_f32_32x32x16_bf16(ones, p0.v, lacc0, 0, 0, 0);
            lacc1 = __builtin_amdgcn_mfma_f32_32x32x16_bf16(ones, p1.v, lacc1, 0, 0, 0);
            // V fragments shared by both tiles
            oacc[0][0] = __builtin_amdgcn_mfma_f32_32x32x16_bf16(p0.v, s2 ? va2 : va0, oacc[0][0], 0, 0, 0);
            oacc[0][1] = __builtin_amdgcn_mfma_f32_32x32x16_bf16(p0.v, s2 ? va3 : va1, oacc[0][1], 0, 0, 0);
            oacc[1][0] = __builtin_amdgcn_mfma_f32_32x32x16_bf16(p1.v, s2 ? va2 : va0, oacc[1][0], 0, 0, 0);
            oacc[1][1] = __builtin_amdgcn_mfma_f32_32x32x16_bf16(p1.v, s2 ? va3 : va1, oacc[1][1], 0, 0, 0);
        }
        ga = gan; va0 = vn0; va1 = vn1; va2 = vn2; va3 = vn3;
    }

    const float lsum0 = lacc0[0];        // all regs equal; sums both hi halves
    const float lsum1 = lacc1[0];

    // ---- epilogue: per-tile tree-combine of 4 wave partials (O^T layout) ----
    if (hi == 0) { Ls[0][wave][col] = lsum0; Ls[1][wave][col] = lsum1; }
    if (wave & 1) {
        float (*Ra)[36] = (wave == 1) ? R0a : R1a;
        float (*Rb)[36] = (wave == 1) ? R0b : R1b;
        #pragma unroll
        for (int ch = 0; ch < 2; ch++)
            #pragma unroll
            for (int r = 0; r < 16; r++) {
                int ii = (r & 3) + 8 * (r >> 2) + 4 * hi;
                Ra[ch * 32 + col][ii] = oacc[0][ch][r];
                Rb[ch * 32 + col][ii] = oacc[1][ch][r];
            }
    }
    __syncthreads();
    if (!(wave & 1)) {
        float (*Ra)[36] = (wave == 0) ? R0a : R1a;
        float (*Rb)[36] = (wave == 0) ? R0b : R1b;
        #pragma unroll
        for (int ch = 0; ch < 2; ch++)
            #pragma unroll
            for (int r = 0; r < 16; r++) {
                int ii = (r & 3) + 8 * (r >> 2) + 4 * hi;
                oacc[0][ch][r] += Ra[ch * 32 + col][ii];
                oacc[1][ch][r] += Rb[ch * 32 + col][ii];
            }
    }
    if (wave == 1 && hi == 0)
        Sc[0][col] = g / (Ls[0][0][col] + Ls[0][1][col] + Ls[0][2][col] + Ls[0][3][col]);
    if (wave == 3 && hi == 0)
        Sc[1][col] = g / (Ls[1][0][col] + Ls[1][1][col] + Ls[1][2][col] + Ls[1][3][col]);
    if (wave == 2) {
        #pragma unroll
        for (int ch = 0; ch < 2; ch++)
            #pragma unroll
            for (int r = 0; r < 16; r++) {
                int ii = (r & 3) + 8 * (r >> 2) + 4 * hi;
                R1a[ch * 32 + col][ii] = oacc[0][ch][r];
                R1b[ch * 32 + col][ii] = oacc[1][ch][r];
            }
    }
    __syncthreads();
    if (wave == 0) {
        #pragma unroll
        for (int ch = 0; ch < 2; ch++)
            #pragma unroll
            for (int r = 0; r < 16; r++) {
                int ii = (r & 3) + 8 * (r >> 2) + 4 * hi;
                R0a[ch * 32 + col][ii] = oacc[0][ch][r] + R1a[ch * 32 + col][ii];
                R0b[ch * 32 + col][ii] = oacc[1][ch][r] + R1b[ch * 32 + col][ii];
            }
    }
    __syncthreads();

    // store: 64 c x 64 i; tile uniform per thread (q<2 -> tile0)
    const int oc = t >> 2, q = t & 3;
    float (*slab)[36] = (q < 2) ? R0a : R0b;
    const float* sc = Sc[q >> 1];
    const float* xr = x   + ((size_t)b * NC + oc) * NN + i0;
    float*    orow  = out + ((size_t)b * NC + oc) * NN + i0;
    #pragma unroll
    for (int e = 0; e < 4; e++) {
        const int il = q * 16 + e * 4;        // 0..63 within block's i-range
        const int ii = (q & 1) * 16 + e * 4;  // 0..31 within tile
        f32x4 o = *(const f32x4*)&slab[oc][ii];
        f32x4 xv = *(const f32x4*)(xr + il);
        f32x4 rv;
        #pragma unroll
        for (int k = 0; k < 4; k++) rv[k] = o[k] * sc[ii + k] + xv[k];
        *(f32x4*)(orow + il) = rv;
    }
}

extern "C" void kernel_launch(void* const* d_in, const int* in_sizes, int n_in,
                              void* d_out, int out_size, void* d_ws, size_t ws_size,
                              hipStream_t stream) {
    const float* x     = (const float*)d_in[0];
    const float* Wf    = (const float*)d_in[1];
    const float* Wg    = (const float*)d_in[2];
    const float* Wh    = (const float*)d_in[3];
    const float* gamma = (const float*)d_in[4];
    float* out = (float*)d_out;

    // layout: Hf first, then Gw, then Qw — so last-iteration prefetch
    // overreads (Hf -> Gw, Gw -> Qw) stay inside the workspace.
    u16* Hf = (u16*)d_ws;                       // [B][256 slices][2][512] frag-order
    u16* Gw = Hf + (size_t)NB * NC * NN;        // [B][N][16] (top 8 zeroed)
    u16* Qw = Gw + (size_t)NB * NN * 16;        // [B][N][16] (top 8 zeroed)

    precompute_qgh<<<dim3(NB, 64), 256, 0, stream>>>(x, Wf, Wg, Wh, Qw, Gw, Hf);
    attention_fused<<<dim3(NB, 64), 256, 0, stream>>>(Qw, Gw, Hf, x, gamma, out);
}

// Round 13
// 101.558 us; speedup vs baseline: 1.1620x; 1.0459x over previous
//
#include <hip/hip_runtime.h>

typedef float f32x4 __attribute__((ext_vector_type(4)));
typedef float f32x16 __attribute__((ext_vector_type(16)));
typedef short s16x8 __attribute__((ext_vector_type(8)));
typedef short s16x4 __attribute__((ext_vector_type(4)));
typedef unsigned short u16;

#define NB 8
#define NC 64
#define NN 4096

// float -> bf16 bits, round-to-nearest-even
__device__ __forceinline__ u16 f2bf_rne(float f) {
    unsigned u = __float_as_uint(f);
    u += 0x7FFFu + ((u >> 16) & 1u);
    return (u16)(u >> 16);
}
__device__ __forceinline__ float bf2f(u16 v) {
    return __uint_as_float(((unsigned)v) << 16);
}
// pack two f32 -> one u32 of 2 bf16 (RNE), lo = first arg
__device__ __forceinline__ unsigned cvt_pk_bf16(float lo, float hi) {
    unsigned r;
    asm("v_cvt_pk_bf16_f32 %0, %1, %2" : "=v"(r) : "v"(lo), "v"(hi));
    return r;
}
// swap: a' = {a.lanes0-31, b.lanes0-31}, b' = {a.lanes32-63, b.lanes32-63}
__device__ __forceinline__ void pl32_swap(unsigned &a, unsigned &b) {
    asm("v_permlane32_swap_b32 %0, %1" : "+v"(a), "+v"(b));
}
// 2^x via the hardware transcendental unit (v_exp_f32).
__device__ __forceinline__ float exp2_hw(float x) {
    return __builtin_amdgcn_exp2f(x);
}

#define Z16 ((f32x16){0.f,0.f,0.f,0.f,0.f,0.f,0.f,0.f,0.f,0.f,0.f,0.f,0.f,0.f,0.f,0.f})

// ---------------------------------------------------------------------------
// Kernel 1 (unchanged): W' = [Wh(64); Wf(8); Wg(8)] @ x[b] via MFMA.
// Wf pre-scaled by log2(e). Qw/Gw: [B][N][16] bf16, top 8 zeroed. H written
// in PV-B-fragment order (Hf). Grid (b, n-tile) -> batch b pinned to XCD b.
// ---------------------------------------------------------------------------
__global__ __launch_bounds__(256, 4)
void precompute_qgh(const float* __restrict__ x,
                    const float* __restrict__ Wf,
                    const float* __restrict__ Wg,
                    const float* __restrict__ Wh,
                    u16* __restrict__ Qw, u16* __restrict__ Gw,
                    u16* __restrict__ Hf)
{
    const int b  = blockIdx.x;           // b fastest -> XCD = b
    const int n0 = blockIdx.y * 64;
    const int t  = threadIdx.x;
    const int wave = t >> 6, lane = t & 63, col = lane & 15, quad = lane >> 4;
    const float* xb = x + (size_t)b * NC * NN;

    __shared__ __align__(16) u16 WL[80][72];
    __shared__ __align__(16) u16 XT[64][72];

    #pragma unroll
    for (int r5 = 0; r5 < 5; r5++) {
        int v = r5 * 256 + t;
        int m = v >> 4, ks = (v & 15) << 2;
        const float* src = (m < 64) ? (Wh + m * 64 + ks)
                         : (m < 72) ? (Wf + (m - 64) * 64 + ks)
                                    : (Wg + (m - 72) * 64 + ks);
        const float scl = (m >= 64 && m < 72) ? 1.44269504088896f : 1.0f;
        f32x4 wv = *(const f32x4*)src;
        *(unsigned*)&WL[m][ks]     = (unsigned)f2bf_rne(wv[0] * scl) | ((unsigned)f2bf_rne(wv[1] * scl) << 16);
        *(unsigned*)&WL[m][ks + 2] = (unsigned)f2bf_rne(wv[2] * scl) | ((unsigned)f2bf_rne(wv[3] * scl) << 16);
    }
    #pragma unroll
    for (int r4 = 0; r4 < 4; r4++) {
        int v = r4 * 256 + t;
        int c = v >> 4, ns = (v & 15) << 2;
        f32x4 xv = *(const f32x4*)(xb + (size_t)c * NN + n0 + ns);
        #pragma unroll
        for (int e = 0; e < 4; e++) XT[ns + e][c] = f2bf_rne(xv[e]);
    }
    __syncthreads();

    const int n = n0 + wave * 16 + col;
    s16x8 bfrag[2], afrag[5][2];
    #pragma unroll
    for (int s = 0; s < 2; s++)
        bfrag[s] = *(const s16x8*)&XT[wave * 16 + col][s * 32 + quad * 8];
    #pragma unroll
    for (int mt = 0; mt < 5; mt++)
        #pragma unroll
        for (int s = 0; s < 2; s++)
            afrag[mt][s] = *(const s16x8*)&WL[mt * 16 + col][s * 32 + quad * 8];

    f32x4 d[5];
    #pragma unroll
    for (int mt = 0; mt < 5; mt++) d[mt] = (f32x4){0.f, 0.f, 0.f, 0.f};
    #pragma unroll
    for (int s = 0; s < 2; s++)
        #pragma unroll
        for (int mt = 0; mt < 5; mt++)
            d[mt] = __builtin_amdgcn_mfma_f32_16x16x32_bf16(afrag[mt][s], bfrag[s], d[mt], 0, 0, 0);

    union { s16x4 v; u16 e[4]; } pk4;
    #pragma unroll
    for (int r = 0; r < 4; r++) pk4.e[r] = f2bf_rne(d[4][r]);
    u16* qgbase = (quad < 2 ? Qw : Gw) + ((size_t)b * NN + n) * 16;
    *(s16x4*)(qgbase + (quad & 1) * 4) = pk4.v;
    if ((quad & 1) == 0) {
        s16x8 z;
        #pragma unroll
        for (int qz = 0; qz < 8; qz++) ((u16*)&z)[qz] = 0;
        *(s16x8*)(qgbase + 8) = z;
    }

    __syncthreads();
    u16 (*Hl)[72] = WL;                    // reuse WL space
    #pragma unroll
    for (int mt = 0; mt < 4; mt++)
        #pragma unroll
        for (int r = 0; r < 4; r++)
            Hl[mt * 16 + quad * 4 + r][wave * 16 + col] = f2bf_rne(d[mt][r]);
    __syncthreads();

    u16* HfB = Hf + (size_t)b * NC * NN + (size_t)blockIdx.y * 4096;
    #pragma unroll
    for (int it = 0; it < 2; it++) {
        int u = it * 256 + t;
        int s_local = u >> 7, chalf = (u >> 6) & 1, l = u & 63;
        s16x8 vv = *(const s16x8*)&Hl[chalf * 32 + (l & 31)][s_local * 16 + (l >> 5) * 8];
        *(s16x8*)(HfB + (size_t)((s_local * 2 + chalf) * 512 + l * 8)) = vv;
    }
}

// ---------------------------------------------------------------------------
// Kernel 2 v13: R8 structure (best: 99.4us) + MANUAL SOFTWARE PIPELINE.
// R12's pragma-unroll + lacc-MFMA both reverted (regressed; absmax doubled).
// The one change vs R8: chunk n+1's QK^T MFMAs are issued one iteration
// early (into T0/T1), before chunk n's PV — so when iteration n+1 starts
// its exp, S has been in flight a full iteration (~1000cyc): the QK latency
// and S-ready wait leave the per-chunk critical path (the R11-counter
// diagnosis: intra-wave dependency stall, all pipes <56%). lsum adds also
// moved after PV issue. +32 VGPR for T (grid-limited occupancy: free).
// Grid (8, 64), 256-thr blocks, batch->XCD pinned; wave = j-quarter,
// 2 Q-tiles/wave; coalesced fragment-ordered Hf loads; reg double-buffer.
// ---------------------------------------------------------------------------
__global__ __launch_bounds__(256, 2)
void attention_fused(const u16* __restrict__ Qw, const u16* __restrict__ Gw,
                     const u16* __restrict__ Hf,
                     const float* __restrict__ x, const float* __restrict__ gamma,
                     float* __restrict__ out)
{
    const int b  = blockIdx.x;           // b fastest -> XCD = b
    const int i0 = blockIdx.y * 64;
    const int t  = threadIdx.x;
    const int wave = t >> 6, lane = t & 63, col = lane & 31, hi = lane >> 5;

    __shared__ __align__(16) float R0a[64][36];   // tile0 slabs
    __shared__ __align__(16) float R1a[64][36];
    __shared__ __align__(16) float R0b[64][36];   // tile1 slabs
    __shared__ __align__(16) float R1b[64][36];
    __shared__ float Ls[2][4][32];
    __shared__ float Sc[2][32];

    const u16* Qb  = Qw + (size_t)b * NN * 16;
    const u16* Gb  = Gw + (size_t)b * NN * 16;
    const u16* Hfb = Hf + (size_t)b * NC * NN;

    const float g = gamma[0];

    // Two Q fragments: B[k=hi*8+kk][n=i]; k>=8 zeros from layout
    s16x8 qf0 = *(const s16x8*)(Qb + (size_t)(i0 + col) * 16 + hi * 8);
    s16x8 qf1 = *(const s16x8*)(Qb + (size_t)(i0 + 32 + col) * 16 + hi * 8);

    f32x16 oacc[2][2];   // [tile][chalf]; all indexing statically unrolled
    oacc[0][0] = Z16; oacc[0][1] = Z16; oacc[1][0] = Z16; oacc[1][1] = Z16;
    float ls0a = 0.f, ls0b = 0.f, ls1a = 0.f, ls1b = 0.f;

    const int jbase = wave * 1024;
    const u16* pvb = Hfb + (size_t)(jbase >> 4) * 1024 + (size_t)lane * 8;
    const u16* gb0 = Gb + (size_t)(jbase + col) * 16 + hi * 8;

    // A = chunk n fragments (feeding PV); B = chunk n+1 fragments.
    // chunk c: G frag at gb0 + c*512, V frags at pvb + c*2048 (u16 offsets).
    // overreads (chunks 32/33 and G of chunk 32 in the last QK) land in the
    // adjacent ws regions (layout Hf -> Gw -> Qw) — benign, results unused.
    s16x8 gaA = *(const s16x8*)(gb0);
    s16x8 vA0 = *(const s16x8*)(pvb);
    s16x8 vA1 = *(const s16x8*)(pvb + 512);
    s16x8 vA2 = *(const s16x8*)(pvb + 1024);
    s16x8 vA3 = *(const s16x8*)(pvb + 1536);
    s16x8 gaB = *(const s16x8*)(gb0 + 512);
    s16x8 vB0 = *(const s16x8*)(pvb + 2048);
    s16x8 vB1 = *(const s16x8*)(pvb + 2048 + 512);
    s16x8 vB2 = *(const s16x8*)(pvb + 2048 + 1024);
    s16x8 vB3 = *(const s16x8*)(pvb + 2048 + 1536);

    // S for chunk 0, issued in the preamble
    f32x16 S0c = __builtin_amdgcn_mfma_f32_32x32x16_bf16(gaA, qf0, Z16, 0, 0, 0);
    f32x16 S1c = __builtin_amdgcn_mfma_f32_32x32x16_bf16(gaA, qf1, Z16, 0, 0, 0);

    for (int cc = 0; cc < 32; cc++) {
        // (1) softmax numerators for chunk cc (S has been in flight 1 iter)
        #pragma unroll
        for (int r = 0; r < 16; r++) S0c[r] = exp2_hw(S0c[r]);
        #pragma unroll
        for (int r = 0; r < 16; r++) S1c[r] = exp2_hw(S1c[r]);

        // (2) QK for chunk cc+1 issued NOW (matrix pipe; result consumed
        //     next iteration — latency fully off the critical path)
        f32x16 T0 = __builtin_amdgcn_mfma_f32_32x32x16_bf16(gaB, qf0, Z16, 0, 0, 0);
        f32x16 T1 = __builtin_amdgcn_mfma_f32_32x32x16_bf16(gaB, qf1, Z16, 0, 0, 0);

        // (3) cvt/swap + PV for chunk cc
        #pragma unroll
        for (int s2 = 0; s2 < 2; s2++) {
            unsigned a0 = cvt_pk_bf16(S0c[8*s2+0], S0c[8*s2+1]);
            unsigned a2 = cvt_pk_bf16(S0c[8*s2+4], S0c[8*s2+5]);
            unsigned a1 = cvt_pk_bf16(S0c[8*s2+2], S0c[8*s2+3]);
            unsigned a3 = cvt_pk_bf16(S0c[8*s2+6], S0c[8*s2+7]);
            pl32_swap(a0, a2);
            pl32_swap(a1, a3);
            union { s16x8 v; unsigned u[4]; } p0;
            p0.u[0] = a0; p0.u[1] = a1; p0.u[2] = a2; p0.u[3] = a3;
            unsigned b0 = cvt_pk_bf16(S1c[8*s2+0], S1c[8*s2+1]);
            unsigned b2 = cvt_pk_bf16(S1c[8*s2+4], S1c[8*s2+5]);
            unsigned b1 = cvt_pk_bf16(S1c[8*s2+2], S1c[8*s2+3]);
            unsigned b3 = cvt_pk_bf16(S1c[8*s2+6], S1c[8*s2+7]);
            pl32_swap(b0, b2);
            pl32_swap(b1, b3);
            union { s16x8 v; unsigned u[4]; } p1;
            p1.u[0] = b0; p1.u[1] = b1; p1.u[2] = b2; p1.u[3] = b3;
            oacc[0][0] = __builtin_amdgcn_mfma_f32_32x32x16_bf16(p0.v, s2 ? vA2 : vA0, oacc[0][0], 0, 0, 0);
            oacc[0][1] = __builtin_amdgcn_mfma_f32_32x32x16_bf16(p0.v, s2 ? vA3 : vA1, oacc[0][1], 0, 0, 0);
            oacc[1][0] = __builtin_amdgcn_mfma_f32_32x32x16_bf16(p1.v, s2 ? vA2 : vA0, oacc[1][0], 0, 0, 0);
            oacc[1][1] = __builtin_amdgcn_mfma_f32_32x32x16_bf16(p1.v, s2 ? vA3 : vA1, oacc[1][1], 0, 0, 0);
        }

        // (4) row-sum adds AFTER PV issue (off the exp->PV path)
        #pragma unroll
        for (int r = 0; r < 16; r += 2) {
            ls0a += S0c[r]; ls0b += S0c[r + 1];
            ls1a += S1c[r]; ls1b += S1c[r + 1];
        }

        // (5) rotate buffers; load chunk cc+2 into B
        gaA = gaB; vA0 = vB0; vA1 = vB1; vA2 = vB2; vA3 = vB3;
        {
            const u16* np = pvb + (size_t)(cc + 2) * 2048;
            gaB = *(const s16x8*)(gb0 + (size_t)(cc + 2) * 512);
            vB0 = *(const s16x8*)(np);
            vB1 = *(const s16x8*)(np + 512);
            vB2 = *(const s16x8*)(np + 1024);
            vB3 = *(const s16x8*)(np + 1536);
        }
        S0c = T0; S1c = T1;
    }

    float lsum0 = ls0a + ls0b;
    float lsum1 = ls1a + ls1b;
    // combine hi-halves (lane i and i+32 hold disjoint j'-sets)
    {
        unsigned a = __float_as_uint(lsum0), c2 = a;
        pl32_swap(a, c2);
        lsum0 = __uint_as_float(a) + __uint_as_float(c2);
        unsigned d = __float_as_uint(lsum1), e2 = d;
        pl32_swap(d, e2);
        lsum1 = __uint_as_float(d) + __uint_as_float(e2);
    }

    // ---- epilogue: per-tile tree-combine of 4 wave partials (O^T layout) ----
    if (hi == 0) { Ls[0][wave][col] = lsum0; Ls[1][wave][col] = lsum1; }
    if (wave & 1) {
        float (*Ra)[36] = (wave == 1) ? R0a : R1a;
        float (*Rb)[36] = (wave == 1) ? R0b : R1b;
        #pragma unroll
        for (int ch = 0; ch < 2; ch++)
            #pragma unroll
            for (int r = 0; r < 16; r++) {
                int ii = (r & 3) + 8 * (r >> 2) + 4 * hi;
                Ra[ch * 32 + col][ii] = oacc[0][ch][r];
                Rb[ch * 32 + col][ii] = oacc[1][ch][r];
            }
    }
    __syncthreads();
    if (!(wave & 1)) {
        float (*Ra)[36] = (wave == 0) ? R0a : R1a;
        float (*Rb)[36] = (wave == 0) ? R0b : R1b;
        #pragma unroll
        for (int ch = 0; ch < 2; ch++)
            #pragma unroll
            for (int r = 0; r < 16; r++) {
                int ii = (r & 3) + 8 * (r >> 2) + 4 * hi;
                oacc[0][ch][r] += Ra[ch * 32 + col][ii];
                oacc[1][ch][r] += Rb[ch * 32 + col][ii];
            }
    }
    if (wave == 1 && hi == 0)
        Sc[0][col] = g / (Ls[0][0][col] + Ls[0][1][col] + Ls[0][2][col] + Ls[0][3][col]);
    if (wave == 3 && hi == 0)
        Sc[1][col] = g / (Ls[1][0][col] + Ls[1][1][col] + Ls[1][2][col] + Ls[1][3][col]);
    if (wave == 2) {
        #pragma unroll
        for (int ch = 0; ch < 2; ch++)
            #pragma unroll
            for (int r = 0; r < 16; r++) {
                int ii = (r & 3) + 8 * (r >> 2) + 4 * hi;
                R1a[ch * 32 + col][ii] = oacc[0][ch][r];
                R1b[ch * 32 + col][ii] = oacc[1][ch][r];
            }
    }
    __syncthreads();
    if (wave == 0) {
        #pragma unroll
        for (int ch = 0; ch < 2; ch++)
            #pragma unroll
            for (int r = 0; r < 16; r++) {
                int ii = (r & 3) + 8 * (r >> 2) + 4 * hi;
                R0a[ch * 32 + col][ii] = oacc[0][ch][r] + R1a[ch * 32 + col][ii];
                R0b[ch * 32 + col][ii] = oacc[1][ch][r] + R1b[ch * 32 + col][ii];
            }
    }
    __syncthreads();

    // store: 64 c x 64 i; tile uniform per thread (q<2 -> tile0)
    const int oc = t >> 2, q = t & 3;
    float (*slab)[36] = (q < 2) ? R0a : R0b;
    const float* sc = Sc[q >> 1];
    const float* xr = x   + ((size_t)b * NC + oc) * NN + i0;
    float*    orow  = out + ((size_t)b * NC + oc) * NN + i0;
    #pragma unroll
    for (int e = 0; e < 4; e++) {
        const int il = q * 16 + e * 4;        // 0..63 within block's i-range
        const int ii = (q & 1) * 16 + e * 4;  // 0..31 within tile
        f32x4 o = *(const f32x4*)&slab[oc][ii];
        f32x4 xv = *(const f32x4*)(xr + il);
        f32x4 rv;
        #pragma unroll
        for (int k = 0; k < 4; k++) rv[k] = o[k] * sc[ii + k] + xv[k];
        *(f32x4*)(orow + il) = rv;
    }
}

extern "C" void kernel_launch(void* const* d_in, const int* in_sizes, int n_in,
                              void* d_out, int out_size, void* d_ws, size_t ws_size,
                              hipStream_t stream) {
    const float* x     = (const float*)d_in[0];
    const float* Wf    = (const float*)d_in[1];
    const float* Wg    = (const float*)d_in[2];
    const float* Wh    = (const float*)d_in[3];
    const float* gamma = (const float*)d_in[4];
    float* out = (float*)d_out;

    // layout: Hf first, then Gw, then Qw — so prefetch overreads
    // (Hf -> Gw, Gw -> Qw) stay inside the workspace.
    u16* Hf = (u16*)d_ws;                       // [B][256 slices][2][512] frag-order
    u16* Gw = Hf + (size_t)NB * NC * NN;        // [B][N][16] (top 8 zeroed)
    u16* Qw = Gw + (size_t)NB * NN * 16;        // [B][N][16] (top 8 zeroed)

    precompute_qgh<<<dim3(NB, 64), 256, 0, stream>>>(x, Wf, Wg, Wh, Qw, Gw, Hf);
    attention_fused<<<dim3(NB, 64), 256, 0, stream>>>(Qw, Gw, Hf, x, gamma, out);
}

// Round 14
// 99.700 us; speedup vs baseline: 1.1836x; 1.0186x over previous
//
#include <hip/hip_runtime.h>

typedef float f32x4 __attribute__((ext_vector_type(4)));
typedef float f32x16 __attribute__((ext_vector_type(16)));
typedef short s16x8 __attribute__((ext_vector_type(8)));
typedef short s16x4 __attribute__((ext_vector_type(4)));
typedef unsigned short u16;

#define NB 8
#define NC 64
#define NN 4096

// float -> bf16 bits, round-to-nearest-even
__device__ __forceinline__ u16 f2bf_rne(float f) {
    unsigned u = __float_as_uint(f);
    u += 0x7FFFu + ((u >> 16) & 1u);
    return (u16)(u >> 16);
}
__device__ __forceinline__ float bf2f(u16 v) {
    return __uint_as_float(((unsigned)v) << 16);
}
// pack two f32 -> one u32 of 2 bf16 (RNE), lo = first arg
__device__ __forceinline__ unsigned cvt_pk_bf16(float lo, float hi) {
    unsigned r;
    asm("v_cvt_pk_bf16_f32 %0, %1, %2" : "=v"(r) : "v"(lo), "v"(hi));
    return r;
}
// swap: a' = {a.lanes0-31, b.lanes0-31}, b' = {a.lanes32-63, b.lanes32-63}
__device__ __forceinline__ void pl32_swap(unsigned &a, unsigned &b) {
    asm("v_permlane32_swap_b32 %0, %1" : "+v"(a), "+v"(b));
}
// 2^x via the hardware transcendental unit (v_exp_f32).
__device__ __forceinline__ float exp2_hw(float x) {
    return __builtin_amdgcn_exp2f(x);
}

#define Z16 ((f32x16){0.f,0.f,0.f,0.f,0.f,0.f,0.f,0.f,0.f,0.f,0.f,0.f,0.f,0.f,0.f,0.f})

// ---------------------------------------------------------------------------
// Kernel 1: W' = [Wh(64); Wf(8); Wg(8)] @ x[b] via MFMA.
// Wf pre-scaled by log2(e). Qw/Gw: [B][N][16] bf16, top 8 zeroed. H written
// in PV-B-fragment order (Hf). Grid (b, n-tile) -> batch b pinned to XCD b.
// v14: Hl gets its own LDS buffer (no WL reuse) -> one barrier dropped.
// 30 KB LDS total, still 4 blocks/CU.
// ---------------------------------------------------------------------------
__global__ __launch_bounds__(256, 4)
void precompute_qgh(const float* __restrict__ x,
                    const float* __restrict__ Wf,
                    const float* __restrict__ Wg,
                    const float* __restrict__ Wh,
                    u16* __restrict__ Qw, u16* __restrict__ Gw,
                    u16* __restrict__ Hf)
{
    const int b  = blockIdx.x;           // b fastest -> XCD = b
    const int n0 = blockIdx.y * 64;
    const int t  = threadIdx.x;
    const int wave = t >> 6, lane = t & 63, col = lane & 15, quad = lane >> 4;
    const float* xb = x + (size_t)b * NC * NN;

    __shared__ __align__(16) u16 WL[80][72];
    __shared__ __align__(16) u16 XT[64][72];
    __shared__ __align__(16) u16 Hl[64][72];

    #pragma unroll
    for (int r5 = 0; r5 < 5; r5++) {
        int v = r5 * 256 + t;
        int m = v >> 4, ks = (v & 15) << 2;
        const float* src = (m < 64) ? (Wh + m * 64 + ks)
                         : (m < 72) ? (Wf + (m - 64) * 64 + ks)
                                    : (Wg + (m - 72) * 64 + ks);
        const float scl = (m >= 64 && m < 72) ? 1.44269504088896f : 1.0f;
        f32x4 wv = *(const f32x4*)src;
        *(unsigned*)&WL[m][ks]     = (unsigned)f2bf_rne(wv[0] * scl) | ((unsigned)f2bf_rne(wv[1] * scl) << 16);
        *(unsigned*)&WL[m][ks + 2] = (unsigned)f2bf_rne(wv[2] * scl) | ((unsigned)f2bf_rne(wv[3] * scl) << 16);
    }
    #pragma unroll
    for (int r4 = 0; r4 < 4; r4++) {
        int v = r4 * 256 + t;
        int c = v >> 4, ns = (v & 15) << 2;
        f32x4 xv = *(const f32x4*)(xb + (size_t)c * NN + n0 + ns);
        #pragma unroll
        for (int e = 0; e < 4; e++) XT[ns + e][c] = f2bf_rne(xv[e]);
    }
    __syncthreads();

    const int n = n0 + wave * 16 + col;
    s16x8 bfrag[2], afrag[5][2];
    #pragma unroll
    for (int s = 0; s < 2; s++)
        bfrag[s] = *(const s16x8*)&XT[wave * 16 + col][s * 32 + quad * 8];
    #pragma unroll
    for (int mt = 0; mt < 5; mt++)
        #pragma unroll
        for (int s = 0; s < 2; s++)
            afrag[mt][s] = *(const s16x8*)&WL[mt * 16 + col][s * 32 + quad * 8];

    f32x4 d[5];
    #pragma unroll
    for (int mt = 0; mt < 5; mt++) d[mt] = (f32x4){0.f, 0.f, 0.f, 0.f};
    #pragma unroll
    for (int s = 0; s < 2; s++)
        #pragma unroll
        for (int mt = 0; mt < 5; mt++)
            d[mt] = __builtin_amdgcn_mfma_f32_16x16x32_bf16(afrag[mt][s], bfrag[s], d[mt], 0, 0, 0);

    union { s16x4 v; u16 e[4]; } pk4;
    #pragma unroll
    for (int r = 0; r < 4; r++) pk4.e[r] = f2bf_rne(d[4][r]);
    u16* qgbase = (quad < 2 ? Qw : Gw) + ((size_t)b * NN + n) * 16;
    *(s16x4*)(qgbase + (quad & 1) * 4) = pk4.v;
    if ((quad & 1) == 0) {
        s16x8 z;
        #pragma unroll
        for (int qz = 0; qz < 8; qz++) ((u16*)&z)[qz] = 0;
        *(s16x8*)(qgbase + 8) = z;
    }

    // H transpose through dedicated Hl buffer (no WAR barrier needed)
    #pragma unroll
    for (int mt = 0; mt < 4; mt++)
        #pragma unroll
        for (int r = 0; r < 4; r++)
            Hl[mt * 16 + quad * 4 + r][wave * 16 + col] = f2bf_rne(d[mt][r]);
    __syncthreads();

    u16* HfB = Hf + (size_t)b * NC * NN + (size_t)blockIdx.y * 4096;
    #pragma unroll
    for (int it = 0; it < 2; it++) {
        int u = it * 256 + t;
        int s_local = u >> 7, chalf = (u >> 6) & 1, l = u & 63;
        s16x8 vv = *(const s16x8*)&Hl[chalf * 32 + (l & 31)][s_local * 16 + (l >> 5) * 8];
        *(s16x8*)(HfB + (size_t)((s_local * 2 + chalf) * 512 + l * 8)) = vv;
    }
}

// ---------------------------------------------------------------------------
// Kernel 2 v14: R8's main loop EXACTLY (best measured total: 99.4us) plus
// two risk-free micro-deltas: (a) lsum adds moved AFTER PV issue (off the
// exp->cvt->PV critical path); (b) s_setprio(1) around the exp/cvt/PV
// compute cluster (guide m191: +4-7% attn; co-resident waves are from
// independent blocks -> phase-diverse). All R9-R13 structural experiments
// reverted (each was neutral or negative vs R8).
// Grid (8, 64), 256-thr blocks, batch->XCD pinned; wave = j-quarter,
// 2 Q-tiles/wave; coalesced fragment-ordered Hf loads; depth-1 reg prefetch.
// ---------------------------------------------------------------------------
__global__ __launch_bounds__(256, 2)
void attention_fused(const u16* __restrict__ Qw, const u16* __restrict__ Gw,
                     const u16* __restrict__ Hf,
                     const float* __restrict__ x, const float* __restrict__ gamma,
                     float* __restrict__ out)
{
    const int b  = blockIdx.x;           // b fastest -> XCD = b
    const int i0 = blockIdx.y * 64;
    const int t  = threadIdx.x;
    const int wave = t >> 6, lane = t & 63, col = lane & 31, hi = lane >> 5;

    __shared__ __align__(16) float R0a[64][36];   // tile0 slabs
    __shared__ __align__(16) float R1a[64][36];
    __shared__ __align__(16) float R0b[64][36];   // tile1 slabs
    __shared__ __align__(16) float R1b[64][36];
    __shared__ float Ls[2][4][32];
    __shared__ float Sc[2][32];

    const u16* Qb  = Qw + (size_t)b * NN * 16;
    const u16* Gb  = Gw + (size_t)b * NN * 16;
    const u16* Hfb = Hf + (size_t)b * NC * NN;

    const float g = gamma[0];

    // Two Q fragments: B[k=hi*8+kk][n=i]; k>=8 zeros from layout
    s16x8 qf0 = *(const s16x8*)(Qb + (size_t)(i0 + col) * 16 + hi * 8);
    s16x8 qf1 = *(const s16x8*)(Qb + (size_t)(i0 + 32 + col) * 16 + hi * 8);

    f32x16 oacc[2][2];   // [tile][chalf]; all indexing statically unrolled
    oacc[0][0] = Z16; oacc[0][1] = Z16; oacc[1][0] = Z16; oacc[1][1] = Z16;
    float ls0a = 0.f, ls0b = 0.f, ls1a = 0.f, ls1b = 0.f;

    const int jbase = wave * 1024;
    const u16* pv = Hfb + (size_t)(jbase >> 4) * 1024 + (size_t)lane * 8;

    // prefetch chunk 0: G A-frag + 4 V B-frags ([slice s2][chalf])
    s16x8 ga  = *(const s16x8*)(Gb + (size_t)(jbase + col) * 16 + hi * 8);
    s16x8 va0 = *(const s16x8*)(pv);
    s16x8 va1 = *(const s16x8*)(pv + 512);
    s16x8 va2 = *(const s16x8*)(pv + 1024);
    s16x8 va3 = *(const s16x8*)(pv + 1536);
    pv += 2048;

    for (int cc = 0; cc < 32; cc++) {
        // prefetch chunk cc+1 (last-iter overread -> adjacent ws region, benign)
        s16x8 gan = *(const s16x8*)(Gb + (size_t)(jbase + cc * 32 + 32 + col) * 16 + hi * 8);
        s16x8 vn0 = *(const s16x8*)(pv);
        s16x8 vn1 = *(const s16x8*)(pv + 512);
        s16x8 vn2 = *(const s16x8*)(pv + 1024);
        s16x8 vn3 = *(const s16x8*)(pv + 1536);
        pv += 2048;

        __builtin_amdgcn_s_setprio(1);
        f32x16 S0 = __builtin_amdgcn_mfma_f32_32x32x16_bf16(ga, qf0, Z16, 0, 0, 0);
        f32x16 S1 = __builtin_amdgcn_mfma_f32_32x32x16_bf16(ga, qf1, Z16, 0, 0, 0);
        #pragma unroll
        for (int r = 0; r < 16; r++) S0[r] = exp2_hw(S0[r]);
        #pragma unroll
        for (int r = 0; r < 16; r++) S1[r] = exp2_hw(S1[r]);

        #pragma unroll
        for (int s2 = 0; s2 < 2; s2++) {
            // tile 0 P fragment
            unsigned a0 = cvt_pk_bf16(S0[8*s2+0], S0[8*s2+1]);
            unsigned a2 = cvt_pk_bf16(S0[8*s2+4], S0[8*s2+5]);
            unsigned a1 = cvt_pk_bf16(S0[8*s2+2], S0[8*s2+3]);
            unsigned a3 = cvt_pk_bf16(S0[8*s2+6], S0[8*s2+7]);
            pl32_swap(a0, a2);
            pl32_swap(a1, a3);
            union { s16x8 v; unsigned u[4]; } p0;
            p0.u[0] = a0; p0.u[1] = a1; p0.u[2] = a2; p0.u[3] = a3;
            // tile 1 P fragment
            unsigned b0 = cvt_pk_bf16(S1[8*s2+0], S1[8*s2+1]);
            unsigned b2 = cvt_pk_bf16(S1[8*s2+4], S1[8*s2+5]);
            unsigned b1 = cvt_pk_bf16(S1[8*s2+2], S1[8*s2+3]);
            unsigned b3 = cvt_pk_bf16(S1[8*s2+6], S1[8*s2+7]);
            pl32_swap(b0, b2);
            pl32_swap(b1, b3);
            union { s16x8 v; unsigned u[4]; } p1;
            p1.u[0] = b0; p1.u[1] = b1; p1.u[2] = b2; p1.u[3] = b3;
            // V fragments shared by both tiles
            oacc[0][0] = __builtin_amdgcn_mfma_f32_32x32x16_bf16(p0.v, s2 ? va2 : va0, oacc[0][0], 0, 0, 0);
            oacc[0][1] = __builtin_amdgcn_mfma_f32_32x32x16_bf16(p0.v, s2 ? va3 : va1, oacc[0][1], 0, 0, 0);
            oacc[1][0] = __builtin_amdgcn_mfma_f32_32x32x16_bf16(p1.v, s2 ? va2 : va0, oacc[1][0], 0, 0, 0);
            oacc[1][1] = __builtin_amdgcn_mfma_f32_32x32x16_bf16(p1.v, s2 ? va3 : va1, oacc[1][1], 0, 0, 0);
        }
        __builtin_amdgcn_s_setprio(0);

        // row-sum adds AFTER PV issue (off the exp->PV critical path)
        #pragma unroll
        for (int r = 0; r < 16; r += 2) {
            ls0a += S0[r]; ls0b += S0[r + 1];
            ls1a += S1[r]; ls1b += S1[r + 1];
        }
        ga = gan; va0 = vn0; va1 = vn1; va2 = vn2; va3 = vn3;
    }

    float lsum0 = ls0a + ls0b;
    float lsum1 = ls1a + ls1b;
    // combine hi-halves (lane i and i+32 hold disjoint j'-sets)
    {
        unsigned a = __float_as_uint(lsum0), c2 = a;
        pl32_swap(a, c2);
        lsum0 = __uint_as_float(a) + __uint_as_float(c2);
        unsigned d = __float_as_uint(lsum1), e2 = d;
        pl32_swap(d, e2);
        lsum1 = __uint_as_float(d) + __uint_as_float(e2);
    }

    // ---- epilogue: per-tile tree-combine of 4 wave partials (O^T layout) ----
    if (hi == 0) { Ls[0][wave][col] = lsum0; Ls[1][wave][col] = lsum1; }
    if (wave & 1) {
        float (*Ra)[36] = (wave == 1) ? R0a : R1a;
        float (*Rb)[36] = (wave == 1) ? R0b : R1b;
        #pragma unroll
        for (int ch = 0; ch < 2; ch++)
            #pragma unroll
            for (int r = 0; r < 16; r++) {
                int ii = (r & 3) + 8 * (r >> 2) + 4 * hi;
                Ra[ch * 32 + col][ii] = oacc[0][ch][r];
                Rb[ch * 32 + col][ii] = oacc[1][ch][r];
            }
    }
    __syncthreads();
    if (!(wave & 1)) {
        float (*Ra)[36] = (wave == 0) ? R0a : R1a;
        float (*Rb)[36] = (wave == 0) ? R0b : R1b;
        #pragma unroll
        for (int ch = 0; ch < 2; ch++)
            #pragma unroll
            for (int r = 0; r < 16; r++) {
                int ii = (r & 3) + 8 * (r >> 2) + 4 * hi;
                oacc[0][ch][r] += Ra[ch * 32 + col][ii];
                oacc[1][ch][r] += Rb[ch * 32 + col][ii];
            }
    }
    if (wave == 1 && hi == 0)
        Sc[0][col] = g / (Ls[0][0][col] + Ls[0][1][col] + Ls[0][2][col] + Ls[0][3][col]);
    if (wave == 3 && hi == 0)
        Sc[1][col] = g / (Ls[1][0][col] + Ls[1][1][col] + Ls[1][2][col] + Ls[1][3][col]);
    if (wave == 2) {
        #pragma unroll
        for (int ch = 0; ch < 2; ch++)
            #pragma unroll
            for (int r = 0; r < 16; r++) {
                int ii = (r & 3) + 8 * (r >> 2) + 4 * hi;
                R1a[ch * 32 + col][ii] = oacc[0][ch][r];
                R1b[ch * 32 + col][ii] = oacc[1][ch][r];
            }
    }
    __syncthreads();
    if (wave == 0) {
        #pragma unroll
        for (int ch = 0; ch < 2; ch++)
            #pragma unroll
            for (int r = 0; r < 16; r++) {
                int ii = (r & 3) + 8 * (r >> 2) + 4 * hi;
                R0a[ch * 32 + col][ii] = oacc[0][ch][r] + R1a[ch * 32 + col][ii];
                R0b[ch * 32 + col][ii] = oacc[1][ch][r] + R1b[ch * 32 + col][ii];
            }
    }
    __syncthreads();

    // store: 64 c x 64 i; tile uniform per thread (q<2 -> tile0)
    const int oc = t >> 2, q = t & 3;
    float (*slab)[36] = (q < 2) ? R0a : R0b;
    const float* sc = Sc[q >> 1];
    const float* xr = x   + ((size_t)b * NC + oc) * NN + i0;
    float*    orow  = out + ((size_t)b * NC + oc) * NN + i0;
    #pragma unroll
    for (int e = 0; e < 4; e++) {
        const int il = q * 16 + e * 4;        // 0..63 within block's i-range
        const int ii = (q & 1) * 16 + e * 4;  // 0..31 within tile
        f32x4 o = *(const f32x4*)&slab[oc][ii];
        f32x4 xv = *(const f32x4*)(xr + il);
        f32x4 rv;
        #pragma unroll
        for (int k = 0; k < 4; k++) rv[k] = o[k] * sc[ii + k] + xv[k];
        *(f32x4*)(orow + il) = rv;
    }
}

extern "C" void kernel_launch(void* const* d_in, const int* in_sizes, int n_in,
                              void* d_out, int out_size, void* d_ws, size_t ws_size,
                              hipStream_t stream) {
    const float* x     = (const float*)d_in[0];
    const float* Wf    = (const float*)d_in[1];
    const float* Wg    = (const float*)d_in[2];
    const float* Wh    = (const float*)d_in[3];
    const float* gamma = (const float*)d_in[4];
    float* out = (float*)d_out;

    // layout: Hf first, then Gw, then Qw — so prefetch overreads
    // (Hf -> Gw, Gw -> Qw) stay inside the workspace.
    u16* Hf = (u16*)d_ws;                       // [B][256 slices][2][512] frag-order
    u16* Gw = Hf + (size_t)NB * NC * NN;        // [B][N][16] (top 8 zeroed)
    u16* Qw = Gw + (size_t)NB * NN * 16;        // [B][N][16] (top 8 zeroed)

    precompute_qgh<<<dim3(NB, 64), 256, 0, stream>>>(x, Wf, Wg, Wh, Qw, Gw, Hf);
    attention_fused<<<dim3(NB, 64), 256, 0, stream>>>(Qw, Gw, Hf, x, gamma, out);
}